// Round 13
// baseline (1089.762 us; speedup 1.0000x reference)
//
#include <hip/hip_runtime.h>

#define DIM 512
#define B_  64
#define L_  2048

typedef unsigned short u16;
typedef float f32x4 __attribute__((ext_vector_type(4)));
typedef short s16x8 __attribute__((ext_vector_type(8)));
typedef short s16x4 __attribute__((ext_vector_type(4)));

__device__ __forceinline__ u16 f2bf(float f) {
  union { float f; unsigned u; } x{f};
  unsigned r = x.u + 0x7FFFu + ((x.u >> 16) & 1u);
  return (u16)(r >> 16);
}

__device__ __forceinline__ float tanh_fast(float x) {
  float e2 = __expf(2.0f * x);
  return 1.0f - 2.0f / (e2 + 1.0f);
}

// ---------- prep: q = query @ Wq^T + bq ; Wr -> bf16 transposed [t][o][32k] ----------
__global__ __launch_bounds__(256) void prep_kernel(
    const float* __restrict__ query, const float* __restrict__ Wq,
    const float* __restrict__ bq, const float* __restrict__ Wr,
    float* __restrict__ q_out, u16* __restrict__ Wrbt) {
  const int blk = blockIdx.x;
  const int tid = threadIdx.x;
  if (blk < 64) {
    __shared__ float qs[DIM];
    for (int i = tid; i < DIM; i += 256) qs[i] = query[blk * DIM + i];
    __syncthreads();
    for (int o = tid; o < DIM; o += 256) {
      const float* w = Wq + o * DIM;
      float acc = 0.f;
      for (int k = 0; k < DIM; k += 4) {
        f32x4 a = *(const f32x4*)&qs[k];
        f32x4 b = *(const f32x4*)&w[k];
        acc += a.x * b.x + a.y * b.y + a.z * b.z + a.w * b.w;
      }
      q_out[blk * DIM + o] = acc + bq[o];
    }
  } else {
    const int c = blk - 64;
    const int flat = c * 4096 + tid * 16;
    const int o = flat >> 9, k0 = flat & 511;
    const int t = k0 >> 5, kk = k0 & 31;
    u16* dst = Wrbt + t * 16384 + o * 32 + kk;
#pragma unroll
    for (int i = 0; i < 4; ++i) {
      f32x4 a = *(const f32x4*)&Wr[flat + i * 4];
      s16x4 o4;
      o4.x = (short)f2bf(a.x); o4.y = (short)f2bf(a.y);
      o4.z = (short)f2bf(a.z); o4.w = (short)f2bf(a.w);
      *(s16x4*)&dst[i * 4] = o4;
    }
  }
}

// ---------- fused GEMM, 4 chunks/block with cross-chunk read pipeline ----------
// 1024 blocks; block = (lc, b0); chunk c -> (b = b0 + 16c, l0 = lc*32).
// Per chunk: cvt+swizzled-stage -> barrier -> ISSUE NEXT CHUNK'S 8 HBM LOADS
// (pinned by sched_barrier(0), live across K-loop -> reads in flight DURING
// compute) -> R9's barrier-free K-loop -> R9 epilogue. Fixes the HBM duty
// cycle: read bursts of chunk c+1 overlap compute/writes of chunk c.
__global__ __launch_bounds__(512, 6) void gemm_fused(
    const float* __restrict__ ref, const u16* __restrict__ Wrbt,
    const float* __restrict__ q, const float* __restrict__ br,
    const float* __restrict__ v, float* __restrict__ e_out,
    float* __restrict__ logits) {
  __shared__ u16 Bs[32 * 520];    // 33,280 B (65 units x 16B per row)
  __shared__ float u_lds[8][32];

  const int blk = blockIdx.x;
  const int lc = blk & 63, b0 = blk >> 6;
  const int l0 = lc * 32;
  const int tid = threadIdx.x, lane = tid & 63, w = tid >> 6;
  const int rr = lane & 15, kg = lane >> 4;
  const int srow = tid >> 7, scol = tid & 127;

  const u16* ap = Wrbt + (w * 64 + rr) * 32 + kg * 8;

  f32x4 sreg[8];
  int b = b0;
#pragma unroll
  for (int p = 0; p < 8; ++p) {
    const int row = p * 4 + srow;
    sreg[p] = __builtin_nontemporal_load(
        (const f32x4*)&ref[((size_t)(l0 + row) * 64 + b) * 512 + scol * 4]);
  }

  for (int c = 0; c < 4; ++c) {
    const int bcur = b;
    // ---- stage: cvt + swizzled ds_write (R9-verified pattern) ----
#pragma unroll
    for (int p = 0; p < 8; ++p) {
      const int row = p * 4 + srow;
      s16x4 o4;
      o4.x = (short)f2bf(sreg[p].x); o4.y = (short)f2bf(sreg[p].y);
      o4.z = (short)f2bf(sreg[p].z); o4.w = (short)f2bf(sreg[p].w);
      const int unit = row * 65 + ((scol >> 1) ^ ((row & 7) << 2));
      *(s16x4*)&Bs[(unit << 3) + ((scol & 1) << 2)] = o4;
    }
    __syncthreads();

    // ---- issue next chunk's HBM loads NOW; pin with sched_barrier ----
    if (c < 3) {
      b += 16;
#pragma unroll
      for (int p = 0; p < 8; ++p) {
        const int row = p * 4 + srow;
        sreg[p] = __builtin_nontemporal_load(
            (const f32x4*)&ref[((size_t)(l0 + row) * 64 + b) * 512 + scol * 4]);
      }
      __builtin_amdgcn_sched_barrier(0);
    }

    // ---- K-loop (R9 body, barrier-free) ----
    f32x4 acc[4][2];
#pragma unroll
    for (int fm = 0; fm < 4; ++fm)
#pragma unroll
      for (int fn = 0; fn < 2; ++fn) acc[fm][fn] = (f32x4){0.f, 0.f, 0.f, 0.f};

    s16x8 A0[4], A1[4];
#pragma unroll
    for (int fm = 0; fm < 4; ++fm) {
      A0[fm] = *(const s16x8*)(ap + 0 * 16384 + fm * 512);
      A1[fm] = *(const s16x8*)(ap + 1 * 16384 + fm * 512);
    }

#pragma unroll
    for (int t = 0; t < 16; ++t) {
      s16x8 bf[2];
#pragma unroll
      for (int fn = 0; fn < 2; ++fn) {
        const int row = fn * 16 + rr;
        const int unit = row * 65 + ((t * 4 + kg) ^ ((row & 7) << 2));
        bf[fn] = *(const s16x8*)&Bs[unit << 3];
      }
      if (t & 1) {
#pragma unroll
        for (int fm = 0; fm < 4; ++fm)
#pragma unroll
          for (int fn = 0; fn < 2; ++fn)
            acc[fm][fn] = __builtin_amdgcn_mfma_f32_16x16x32_bf16(bf[fn], A1[fm], acc[fm][fn], 0, 0, 0);
        if (t + 2 < 16)
#pragma unroll
          for (int fm = 0; fm < 4; ++fm)
            A1[fm] = *(const s16x8*)(ap + (t + 2) * 16384 + fm * 512);
      } else {
#pragma unroll
        for (int fm = 0; fm < 4; ++fm)
#pragma unroll
          for (int fn = 0; fn < 2; ++fn)
            acc[fm][fn] = __builtin_amdgcn_mfma_f32_16x16x32_bf16(bf[fn], A0[fm], acc[fm][fn], 0, 0, 0);
        if (t + 2 < 16)
#pragma unroll
          for (int fm = 0; fm < 4; ++fm)
            A0[fm] = *(const s16x8*)(ap + (t + 2) * 16384 + fm * 512);
      }
    }

    // ---- epilogue: e = acc + br ; u = sum_o v * tanh(acc + q + br) ----
    f32x4 usA[2];
#pragma unroll
    for (int fn = 0; fn < 2; ++fn) usA[fn] = (f32x4){0.f, 0.f, 0.f, 0.f};
#pragma unroll
    for (int fm = 0; fm < 4; ++fm) {
      const int o = w * 64 + fm * 16 + rr;
      const float brv = br[o];
      const float qv = q[bcur * DIM + o] + brv;
      const float vv = v[o];
      const size_t erow = ((size_t)(bcur * DIM + o)) * L_;
#pragma unroll
      for (int fn = 0; fn < 2; ++fn) {
        const int lb = l0 + fn * 16 + kg * 4;
        f32x4 a = acc[fm][fn];
        f32x4 ev = a + brv;
        *(f32x4*)&e_out[erow + lb] = ev;
        f32x4 th;
        th.x = tanh_fast(a.x + qv);
        th.y = tanh_fast(a.y + qv);
        th.z = tanh_fast(a.z + qv);
        th.w = tanh_fast(a.w + qv);
        usA[fn] += vv * th;
      }
    }
#pragma unroll
    for (int fn = 0; fn < 2; ++fn) {
      f32x4 us = usA[fn];
#pragma unroll
      for (int msk = 1; msk <= 8; msk <<= 1) {  // reduce over rr (o dim)
        us.x += __shfl_xor(us.x, msk);
        us.y += __shfl_xor(us.y, msk);
        us.z += __shfl_xor(us.z, msk);
        us.w += __shfl_xor(us.w, msk);
      }
      if (rr == 0)
        *(f32x4*)&u_lds[w][fn * 16 + kg * 4] = us;
    }
    __syncthreads();  // u_lds ready; also guarantees all Bs reads done
    if (tid < 32) {
      float s = 0.f;
#pragma unroll
      for (int ww = 0; ww < 8; ++ww) s += u_lds[ww][tid];
      logits[(size_t)bcur * L_ + l0 + tid] = s;
    }
  }
}

extern "C" void kernel_launch(void* const* d_in, const int* in_sizes, int n_in,
                              void* d_out, int out_size, void* d_ws, size_t ws_size,
                              hipStream_t stream) {
  const float* query = (const float*)d_in[0];
  const float* ref   = (const float*)d_in[1];
  const float* Wq    = (const float*)d_in[2];
  const float* bq    = (const float*)d_in[3];
  const float* Wr    = (const float*)d_in[4];
  const float* br    = (const float*)d_in[5];
  const float* v     = (const float*)d_in[6];

  float* e_out  = (float*)d_out;
  float* logits = e_out + (size_t)B_ * DIM * L_;  // 67108864

  char* ws = (char*)d_ws;
  u16*   Wrbt = (u16*)ws;               // 512 KB [16][512][32]
  float* q    = (float*)(ws + 524288);  // 128 KB

  prep_kernel<<<128, 256, 0, stream>>>(query, Wq, bq, Wr, q, Wrbt);
  gemm_fused<<<1024, 512, 0, stream>>>(ref, Wrbt, q, br, v, e_out, logits);
}

// Round 14
// 271.757 us; speedup vs baseline: 4.0101x; 4.0101x over previous
//
#include <hip/hip_runtime.h>

#define DIM 512
#define B_  64
#define L_  2048

typedef unsigned short u16;
typedef float f32x4 __attribute__((ext_vector_type(4)));
typedef short s16x8 __attribute__((ext_vector_type(8)));
typedef short s16x4 __attribute__((ext_vector_type(4)));

__device__ __forceinline__ u16 f2bf(float f) {
  union { float f; unsigned u; } x{f};
  unsigned r = x.u + 0x7FFFu + ((x.u >> 16) & 1u);
  return (u16)(r >> 16);
}

__device__ __forceinline__ float tanh_fast(float x) {
  float e2 = __expf(2.0f * x);
  return 1.0f - 2.0f / (e2 + 1.0f);
}

// ---------- prep: q = query @ Wq^T + bq ; Wr -> bf16 transposed [t][o][32k] ----------
__global__ __launch_bounds__(256) void prep_kernel(
    const float* __restrict__ query, const float* __restrict__ Wq,
    const float* __restrict__ bq, const float* __restrict__ Wr,
    float* __restrict__ q_out, u16* __restrict__ Wrbt) {
  const int blk = blockIdx.x;
  const int tid = threadIdx.x;
  if (blk < 64) {
    __shared__ float qs[DIM];
    for (int i = tid; i < DIM; i += 256) qs[i] = query[blk * DIM + i];
    __syncthreads();
    for (int o = tid; o < DIM; o += 256) {
      const float* w = Wq + o * DIM;
      float acc = 0.f;
      for (int k = 0; k < DIM; k += 4) {
        f32x4 a = *(const f32x4*)&qs[k];
        f32x4 b = *(const f32x4*)&w[k];
        acc += a.x * b.x + a.y * b.y + a.z * b.z + a.w * b.w;
      }
      q_out[blk * DIM + o] = acc + bq[o];
    }
  } else {
    const int c = blk - 64;
    const int flat = c * 4096 + tid * 16;
    const int o = flat >> 9, k0 = flat & 511;
    const int t = k0 >> 5, kk = k0 & 31;
    u16* dst = Wrbt + t * 16384 + o * 32 + kk;
#pragma unroll
    for (int i = 0; i < 4; ++i) {
      f32x4 a = *(const f32x4*)&Wr[flat + i * 4];
      s16x4 o4;
      o4.x = (short)f2bf(a.x); o4.y = (short)f2bf(a.y);
      o4.z = (short)f2bf(a.z); o4.w = (short)f2bf(a.w);
      *(s16x4*)&dst[i * 4] = o4;
    }
  }
}

// ---------- fused GEMM: block = 512o x 64l, continuous ref streaming ----------
// grid (32 lt, 64 b). 8 o-waves; wave = 64o x 64l, acc[4][4]. Per K-step:
// issue next ref slice (1 f32x4/thread, nt) -> af (L2-hot Wrbt) + bf (LDS,
// pitch-40) -> 16 MFMA -> cvt+ds_write other buffer -> barrier. ref read ONCE
// from HBM, spread evenly across the kernel (R12's 2.77 TB/s property) with
// no og re-read (R12's flaw). Nothing lives across the loop except acc.
__global__ __launch_bounds__(512, 4) void gemm_fused(
    const float* __restrict__ ref, const u16* __restrict__ Wrbt,
    const float* __restrict__ q, const float* __restrict__ br,
    const float* __restrict__ v, float* __restrict__ e_out,
    float* __restrict__ logits) {
  __shared__ u16 Bs[2][64 * 40];   // 10,240 B: 64 l-rows x 32 k, pitch 40 (80B, 16B-aligned)
  __shared__ float u_lds[8][64];

  const int lt = blockIdx.x, b = blockIdx.y;
  const int l0 = lt * 64;
  const int tid = threadIdx.x, lane = tid & 63, wid = tid >> 6;
  const int rr = lane & 15, kg = lane >> 4;
  const int srow = tid >> 3, sc8 = tid & 7;   // stage map: 64 rows x 8 x f32x4

  const size_t refbase = ((size_t)l0 * 64 + b) * 512;  // + row*32768 + t*32 + sc8*4
  const u16* ap = Wrbt + (wid * 64 + rr) * 32 + kg * 8;

  // ---- prologue: stage t=0 ----
  {
    f32x4 a = __builtin_nontemporal_load(
        (const f32x4*)&ref[refbase + (size_t)srow * 32768 + sc8 * 4]);
    s16x4 o4;
    o4.x = (short)f2bf(a.x); o4.y = (short)f2bf(a.y);
    o4.z = (short)f2bf(a.z); o4.w = (short)f2bf(a.w);
    *(s16x4*)&Bs[0][srow * 40 + sc8 * 4] = o4;
  }
  __syncthreads();

  f32x4 acc[4][4];
#pragma unroll
  for (int fm = 0; fm < 4; ++fm)
#pragma unroll
    for (int fn = 0; fn < 4; ++fn) acc[fm][fn] = (f32x4){0.f, 0.f, 0.f, 0.f};

  for (int t = 0; t < 16; ++t) {
    const int cur = t & 1;
    f32x4 sr;
    if (t < 15) {  // issue next ref slice early: in flight during MFMA
      sr = __builtin_nontemporal_load(
          (const f32x4*)&ref[refbase + (size_t)srow * 32768 + (t + 1) * 32 + sc8 * 4]);
    }
    s16x8 af[4], bf[4];
#pragma unroll
    for (int fm = 0; fm < 4; ++fm)
      af[fm] = *(const s16x8*)(ap + t * 16384 + fm * 512);
#pragma unroll
    for (int fn = 0; fn < 4; ++fn)
      bf[fn] = *(const s16x8*)&Bs[cur][(fn * 16 + rr) * 40 + kg * 8];
#pragma unroll
    for (int fm = 0; fm < 4; ++fm)
#pragma unroll
      for (int fn = 0; fn < 4; ++fn)
        acc[fm][fn] = __builtin_amdgcn_mfma_f32_16x16x32_bf16(bf[fn], af[fm], acc[fm][fn], 0, 0, 0);
    if (t < 15) {  // cvt + stage into other buffer
      s16x4 o4;
      o4.x = (short)f2bf(sr.x); o4.y = (short)f2bf(sr.y);
      o4.z = (short)f2bf(sr.z); o4.w = (short)f2bf(sr.w);
      *(s16x4*)&Bs[cur ^ 1][srow * 40 + sc8 * 4] = o4;
    }
    __syncthreads();
  }

  // ---- epilogue: e = acc + br ; u = sum_o v * tanh(acc + q + br) ----
  f32x4 usA[4];
#pragma unroll
  for (int fn = 0; fn < 4; ++fn) usA[fn] = (f32x4){0.f, 0.f, 0.f, 0.f};
#pragma unroll
  for (int fm = 0; fm < 4; ++fm) {
    const int o = wid * 64 + fm * 16 + rr;
    const float brv = br[o];
    const float qv = q[b * DIM + o] + brv;
    const float vv = v[o];
    const size_t erow = ((size_t)(b * DIM + o)) * L_;
#pragma unroll
    for (int fn = 0; fn < 4; ++fn) {
      const int lb = l0 + fn * 16 + kg * 4;
      f32x4 a = acc[fm][fn];
      f32x4 ev = a + brv;
      *(f32x4*)&e_out[erow + lb] = ev;
      f32x4 th;
      th.x = tanh_fast(a.x + qv);
      th.y = tanh_fast(a.y + qv);
      th.z = tanh_fast(a.z + qv);
      th.w = tanh_fast(a.w + qv);
      usA[fn] += vv * th;
    }
  }
#pragma unroll
  for (int fn = 0; fn < 4; ++fn) {
    f32x4 us = usA[fn];
#pragma unroll
    for (int msk = 1; msk <= 8; msk <<= 1) {  // reduce over rr (o dim)
      us.x += __shfl_xor(us.x, msk);
      us.y += __shfl_xor(us.y, msk);
      us.z += __shfl_xor(us.z, msk);
      us.w += __shfl_xor(us.w, msk);
    }
    if (rr == 0)
      *(f32x4*)&u_lds[wid][fn * 16 + kg * 4] = us;
  }
  __syncthreads();
  if (tid < 64) {
    float s = 0.f;
#pragma unroll
    for (int ww = 0; ww < 8; ++ww) s += u_lds[ww][tid];
    logits[(size_t)b * L_ + l0 + tid] = s;
  }
}

extern "C" void kernel_launch(void* const* d_in, const int* in_sizes, int n_in,
                              void* d_out, int out_size, void* d_ws, size_t ws_size,
                              hipStream_t stream) {
  const float* query = (const float*)d_in[0];
  const float* ref   = (const float*)d_in[1];
  const float* Wq    = (const float*)d_in[2];
  const float* bq    = (const float*)d_in[3];
  const float* Wr    = (const float*)d_in[4];
  const float* br    = (const float*)d_in[5];
  const float* v     = (const float*)d_in[6];

  float* e_out  = (float*)d_out;
  float* logits = e_out + (size_t)B_ * DIM * L_;  // 67108864

  char* ws = (char*)d_ws;
  u16*   Wrbt = (u16*)ws;               // 512 KB [16][512][32]
  float* q    = (float*)(ws + 524288);  // 128 KB

  prep_kernel<<<128, 256, 0, stream>>>(query, Wq, bq, Wr, q, Wrbt);
  gemm_fused<<<dim3(32, 64), 512, 0, stream>>>(ref, Wrbt, q, br, v, e_out, logits);
}

// Round 15
// 226.220 us; speedup vs baseline: 4.8173x; 1.2013x over previous
//
#include <hip/hip_runtime.h>

#define DIM 512
#define B_  64
#define L_  2048

typedef unsigned short u16;
typedef float f32x4 __attribute__((ext_vector_type(4)));
typedef short s16x8 __attribute__((ext_vector_type(8)));
typedef short s16x4 __attribute__((ext_vector_type(4)));

__device__ __forceinline__ u16 f2bf(float f) {
  union { float f; unsigned u; } x{f};
  unsigned r = x.u + 0x7FFFu + ((x.u >> 16) & 1u);
  return (u16)(r >> 16);
}

__device__ __forceinline__ float tanh_fast(float x) {
  float e2 = __expf(2.0f * x);
  return 1.0f - 2.0f / (e2 + 1.0f);
}

// ---------- prep: q = query @ Wq^T + bq ; Wr -> bf16 transposed [t][o][32k] ----------
__global__ __launch_bounds__(256) void prep_kernel(
    const float* __restrict__ query, const float* __restrict__ Wq,
    const float* __restrict__ bq, const float* __restrict__ Wr,
    float* __restrict__ q_out, u16* __restrict__ Wrbt) {
  const int blk = blockIdx.x;
  const int tid = threadIdx.x;
  if (blk < 64) {
    __shared__ float qs[DIM];
    for (int i = tid; i < DIM; i += 256) qs[i] = query[blk * DIM + i];
    __syncthreads();
    for (int o = tid; o < DIM; o += 256) {
      const float* w = Wq + o * DIM;
      float acc = 0.f;
      for (int k = 0; k < DIM; k += 4) {
        f32x4 a = *(const f32x4*)&qs[k];
        f32x4 b = *(const f32x4*)&w[k];
        acc += a.x * b.x + a.y * b.y + a.z * b.z + a.w * b.w;
      }
      q_out[blk * DIM + o] = acc + bq[o];
    }
  } else {
    const int c = blk - 64;
    const int flat = c * 4096 + tid * 16;
    const int o = flat >> 9, k0 = flat & 511;
    const int t = k0 >> 5, kk = k0 & 31;
    u16* dst = Wrbt + t * 16384 + o * 32 + kk;
#pragma unroll
    for (int i = 0; i < 4; ++i) {
      f32x4 a = *(const f32x4*)&Wr[flat + i * 4];
      s16x4 o4;
      o4.x = (short)f2bf(a.x); o4.y = (short)f2bf(a.y);
      o4.z = (short)f2bf(a.z); o4.w = (short)f2bf(a.w);
      *(s16x4*)&dst[i * 4] = o4;
    }
  }
}

// ---------- fused GEMM: 512o x 128l, streaming reads + repacked full-line writes ----------
// grid (64 b, 16 lt), 1024 threads = 16 waves (8 og x 2 lg), wave = 64o x 64l
// (acc[4][4], R14-verified frag math: 64 VGPR + 64 AGPR). Per K-step: issue next
// ref slice (1 f32x4/thread, in flight during MFMA) -> af (L2-hot Wrbt) + bf
// (LDS pitch-40) -> 16 MFMA -> cvt+ds_write dbuf -> barrier. ref read ONCE.
// Epilogue: tanh/logits partials in-register; e stored via 16 ping-pong LDS
// repack phases -> each store instr = 2 rows x 512 B contiguous (R12-proven).
__global__ __launch_bounds__(1024, 4) void gemm_fused(
    const float* __restrict__ ref, const u16* __restrict__ Wrbt,
    const float* __restrict__ q, const float* __restrict__ br,
    const float* __restrict__ v, float* __restrict__ e_out,
    float* __restrict__ logits) {
  __shared__ u16 Bs[2][128 * 40];      // 20,480 B: 128 l-rows x 32 k, pitch 40
  __shared__ float Ebuf[2][32 * 132];  // 33,792 B: repack, pitch 132
  __shared__ float u_lds[16][64];      //  4,096 B

  const int b = blockIdx.x, lt = blockIdx.y;
  const int l0 = lt * 128;
  const int tid = threadIdx.x, lane = tid & 63, wid = tid >> 6;
  const int og = wid >> 1, lg = wid & 1;
  const int rr = lane & 15, kg = lane >> 4;
  const int srow = tid >> 3, sc8 = tid & 7;  // stage: 128 rows x 8 f32x4

  const size_t refbase = ((size_t)(l0 + srow) * 64 + b) * 512 + sc8 * 4;
  const u16* ap = Wrbt + (og * 64 + rr) * 32 + kg * 8;

  // ---- prologue: stage t=0 ----
  {
    f32x4 a = __builtin_nontemporal_load((const f32x4*)&ref[refbase]);
    s16x4 o4;
    o4.x = (short)f2bf(a.x); o4.y = (short)f2bf(a.y);
    o4.z = (short)f2bf(a.z); o4.w = (short)f2bf(a.w);
    *(s16x4*)&Bs[0][srow * 40 + sc8 * 4] = o4;
  }
  __syncthreads();

  f32x4 acc[4][4];
#pragma unroll
  for (int fm = 0; fm < 4; ++fm)
#pragma unroll
    for (int fn = 0; fn < 4; ++fn) acc[fm][fn] = (f32x4){0.f, 0.f, 0.f, 0.f};

  for (int t = 0; t < 16; ++t) {
    const int cur = t & 1;
    f32x4 sr;
    if (t < 15) {  // next ref slice in flight during MFMA
      sr = __builtin_nontemporal_load((const f32x4*)&ref[refbase + (t + 1) * 32]);
    }
    s16x8 af[4], bf[4];
#pragma unroll
    for (int fm = 0; fm < 4; ++fm)
      af[fm] = *(const s16x8*)(ap + t * 16384 + fm * 512);
#pragma unroll
    for (int fn = 0; fn < 4; ++fn)
      bf[fn] = *(const s16x8*)&Bs[cur][(lg * 64 + fn * 16 + rr) * 40 + kg * 8];
#pragma unroll
    for (int fm = 0; fm < 4; ++fm)
#pragma unroll
      for (int fn = 0; fn < 4; ++fn)
        acc[fm][fn] = __builtin_amdgcn_mfma_f32_16x16x32_bf16(bf[fn], af[fm], acc[fm][fn], 0, 0, 0);
    if (t < 15) {
      s16x4 o4;
      o4.x = (short)f2bf(sr.x); o4.y = (short)f2bf(sr.y);
      o4.z = (short)f2bf(sr.z); o4.w = (short)f2bf(sr.w);
      *(s16x4*)&Bs[cur ^ 1][srow * 40 + sc8 * 4] = o4;
    }
    __syncthreads();
  }

  // ---- tanh / logits partials (register-only) ----
  float bb[4];
  f32x4 usA[4];
#pragma unroll
  for (int fn = 0; fn < 4; ++fn) usA[fn] = (f32x4){0.f, 0.f, 0.f, 0.f};
#pragma unroll
  for (int fm = 0; fm < 4; ++fm) {
    const int o = og * 64 + fm * 16 + rr;
    bb[fm] = br[o];
    const float qv = q[b * DIM + o] + bb[fm];
    const float vv = v[o];
#pragma unroll
    for (int fn = 0; fn < 4; ++fn) {
      f32x4 a = acc[fm][fn];
      f32x4 th;
      th.x = tanh_fast(a.x + qv);
      th.y = tanh_fast(a.y + qv);
      th.z = tanh_fast(a.z + qv);
      th.w = tanh_fast(a.w + qv);
      usA[fn] += vv * th;
    }
  }
#pragma unroll
  for (int fn = 0; fn < 4; ++fn) {
    f32x4 us = usA[fn];
#pragma unroll
    for (int msk = 1; msk <= 8; msk <<= 1) {  // reduce over rr (o dim)
      us.x += __shfl_xor(us.x, msk);
      us.y += __shfl_xor(us.y, msk);
      us.z += __shfl_xor(us.z, msk);
      us.w += __shfl_xor(us.w, msk);
    }
    if (rr == 0)
      *(f32x4*)&u_lds[wid][fn * 16 + kg * 4] = us;
  }

  // ---- e-store: 16 ping-pong repack phases; store = 2 rows x 512 B ----
#pragma unroll 2
  for (int ph = 0; ph < 16; ++ph) {
    float* Eb = &Ebuf[ph & 1][0];
    if (og == (ph >> 1)) {
      const int f2b = (ph & 1) * 2;
#pragma unroll
      for (int f2 = 0; f2 < 2; ++f2) {
        const int fm = f2b + f2;
#pragma unroll
        for (int fn = 0; fn < 4; ++fn) {
          f32x4 ev = acc[fm][fn] + bb[fm];
          *(f32x4*)&Eb[(f2 * 16 + rr) * 132 + lg * 64 + fn * 16 + kg * 4] = ev;
        }
      }
    }
    __syncthreads();
    {
      const int op = tid >> 5, lc4 = (tid & 31) * 4;
      f32x4 ev = *(const f32x4*)&Eb[op * 132 + lc4];
      __builtin_nontemporal_store(
          ev, (f32x4*)&e_out[((size_t)(b * DIM + ph * 32 + op)) * L_ + l0 + lc4]);
    }
  }

  // ---- logits ----
  __syncthreads();
  if (tid < 128) {
    const int ll = tid & 63, lgi = tid >> 6;
    float s = 0.f;
#pragma unroll
    for (int o8 = 0; o8 < 8; ++o8) s += u_lds[o8 * 2 + lgi][ll];
    logits[(size_t)b * L_ + l0 + lgi * 64 + ll] = s;
  }
}

extern "C" void kernel_launch(void* const* d_in, const int* in_sizes, int n_in,
                              void* d_out, int out_size, void* d_ws, size_t ws_size,
                              hipStream_t stream) {
  const float* query = (const float*)d_in[0];
  const float* ref   = (const float*)d_in[1];
  const float* Wq    = (const float*)d_in[2];
  const float* bq    = (const float*)d_in[3];
  const float* Wr    = (const float*)d_in[4];
  const float* br    = (const float*)d_in[5];
  const float* v     = (const float*)d_in[6];

  float* e_out  = (float*)d_out;
  float* logits = e_out + (size_t)B_ * DIM * L_;  // 67108864

  char* ws = (char*)d_ws;
  u16*   Wrbt = (u16*)ws;               // 512 KB [16][512][32]
  float* q    = (float*)(ws + 524288);  // 128 KB

  prep_kernel<<<128, 256, 0, stream>>>(query, Wq, bq, Wr, q, Wrbt);
  gemm_fused<<<dim3(64, 16), 1024, 0, stream>>>(ref, Wrbt, q, br, v, e_out, logits);
}

// Round 16
// 222.954 us; speedup vs baseline: 4.8878x; 1.0146x over previous
//
#include <hip/hip_runtime.h>

#define DIM 512
#define B_  64
#define L_  2048

typedef unsigned short u16;
typedef float f32x4 __attribute__((ext_vector_type(4)));
typedef short s16x8 __attribute__((ext_vector_type(8)));
typedef short s16x4 __attribute__((ext_vector_type(4)));

__device__ __forceinline__ u16 f2bf(float f) {
  union { float f; unsigned u; } x{f};
  unsigned r = x.u + 0x7FFFu + ((x.u >> 16) & 1u);
  return (u16)(r >> 16);
}

__device__ __forceinline__ float tanh_fast(float x) {
  float e2 = __expf(2.0f * x);
  return 1.0f - 2.0f / (e2 + 1.0f);
}

// ---------- prep: q = query @ Wq^T + bq ; Wr -> bf16 transposed [t][o][32k] ----------
__global__ __launch_bounds__(256) void prep_kernel(
    const float* __restrict__ query, const float* __restrict__ Wq,
    const float* __restrict__ bq, const float* __restrict__ Wr,
    float* __restrict__ q_out, u16* __restrict__ Wrbt) {
  const int blk = blockIdx.x;
  const int tid = threadIdx.x;
  if (blk < 64) {
    __shared__ float qs[DIM];
    for (int i = tid; i < DIM; i += 256) qs[i] = query[blk * DIM + i];
    __syncthreads();
    for (int o = tid; o < DIM; o += 256) {
      const float* w = Wq + o * DIM;
      float acc = 0.f;
      for (int k = 0; k < DIM; k += 4) {
        f32x4 a = *(const f32x4*)&qs[k];
        f32x4 b = *(const f32x4*)&w[k];
        acc += a.x * b.x + a.y * b.y + a.z * b.z + a.w * b.w;
      }
      q_out[blk * DIM + o] = acc + bq[o];
    }
  } else {
    const int c = blk - 64;
    const int flat = c * 4096 + tid * 16;
    const int o = flat >> 9, k0 = flat & 511;
    const int t = k0 >> 5, kk = k0 & 31;
    u16* dst = Wrbt + t * 16384 + o * 32 + kk;
#pragma unroll
    for (int i = 0; i < 4; ++i) {
      f32x4 a = *(const f32x4*)&Wr[flat + i * 4];
      s16x4 o4;
      o4.x = (short)f2bf(a.x); o4.y = (short)f2bf(a.y);
      o4.z = (short)f2bf(a.z); o4.w = (short)f2bf(a.w);
      *(s16x4*)&dst[i * 4] = o4;
    }
  }
}

// ---------- fused GEMM: 512o x 128l, depth-2 prefetch + counted barrier ----------
// R15 structure; K-loop uses raw s_barrier with lgkmcnt(0) ONLY (no vmcnt drain)
// so the depth-2 ref prefetch (issued at t for use at t+2) stays in flight
// across barriers -- the m201/T3-T4 counted-wait pattern. 8 extra VGPR.
__global__ __launch_bounds__(1024, 4) void gemm_fused(
    const float* __restrict__ ref, const u16* __restrict__ Wrbt,
    const float* __restrict__ q, const float* __restrict__ br,
    const float* __restrict__ v, float* __restrict__ e_out,
    float* __restrict__ logits) {
  __shared__ u16 Bs[2][128 * 40];      // 20,480 B: 128 l-rows x 32 k, pitch 40
  __shared__ float Ebuf[2][32 * 132];  // 33,792 B: repack, pitch 132
  __shared__ float u_lds[16][64];      //  4,096 B

  const int b = blockIdx.x, lt = blockIdx.y;
  const int l0 = lt * 128;
  const int tid = threadIdx.x, lane = tid & 63, wid = tid >> 6;
  const int og = wid >> 1, lg = wid & 1;
  const int rr = lane & 15, kg = lane >> 4;
  const int srow = tid >> 3, sc8 = tid & 7;  // stage: 128 rows x 8 f32x4

  const size_t refbase = ((size_t)(l0 + srow) * 64 + b) * 512 + sc8 * 4;
  const u16* ap = Wrbt + (og * 64 + rr) * 32 + kg * 8;

  // ---- prologue: stage slice 0; issue slice 1 (stays in flight across barrier) ----
  f32x4 srIF;
  {
    f32x4 a = __builtin_nontemporal_load((const f32x4*)&ref[refbase]);
    s16x4 o4;
    o4.x = (short)f2bf(a.x); o4.y = (short)f2bf(a.y);
    o4.z = (short)f2bf(a.z); o4.w = (short)f2bf(a.w);
    *(s16x4*)&Bs[0][srow * 40 + sc8 * 4] = o4;
    srIF = __builtin_nontemporal_load((const f32x4*)&ref[refbase + 32]);
  }
  asm volatile("s_waitcnt lgkmcnt(0)" ::: "memory");
  __builtin_amdgcn_s_barrier();
  __builtin_amdgcn_sched_barrier(0);

  f32x4 acc[4][4];
#pragma unroll
  for (int fm = 0; fm < 4; ++fm)
#pragma unroll
    for (int fn = 0; fn < 4; ++fn) acc[fm][fn] = (f32x4){0.f, 0.f, 0.f, 0.f};

  for (int t = 0; t < 16; ++t) {
    const int cur = t & 1;
    f32x4 srN;
    if (t < 14) {  // depth-2: slice t+2, in flight for ~2 full steps
      srN = __builtin_nontemporal_load((const f32x4*)&ref[refbase + (t + 2) * 32]);
    }
    s16x8 af[4], bf[4];
#pragma unroll
    for (int fm = 0; fm < 4; ++fm)
      af[fm] = *(const s16x8*)(ap + t * 16384 + fm * 512);
#pragma unroll
    for (int fn = 0; fn < 4; ++fn)
      bf[fn] = *(const s16x8*)&Bs[cur][(lg * 64 + fn * 16 + rr) * 40 + kg * 8];
#pragma unroll
    for (int fm = 0; fm < 4; ++fm)
#pragma unroll
      for (int fn = 0; fn < 4; ++fn)
        acc[fm][fn] = __builtin_amdgcn_mfma_f32_16x16x32_bf16(bf[fn], af[fm], acc[fm][fn], 0, 0, 0);
    if (t < 15) {  // stage slice t+1 (loaded one full step ago)
      s16x4 o4;
      o4.x = (short)f2bf(srIF.x); o4.y = (short)f2bf(srIF.y);
      o4.z = (short)f2bf(srIF.z); o4.w = (short)f2bf(srIF.w);
      *(s16x4*)&Bs[cur ^ 1][srow * 40 + sc8 * 4] = o4;
      // counted barrier: ds_write visible, vmcnt NOT drained (prefetch crosses)
      asm volatile("s_waitcnt lgkmcnt(0)" ::: "memory");
      __builtin_amdgcn_s_barrier();
      __builtin_amdgcn_sched_barrier(0);
    }
    srIF = srN;
  }

  // ---- tanh / logits partials (register-only) ----
  float bb[4];
  f32x4 usA[4];
#pragma unroll
  for (int fn = 0; fn < 4; ++fn) usA[fn] = (f32x4){0.f, 0.f, 0.f, 0.f};
#pragma unroll
  for (int fm = 0; fm < 4; ++fm) {
    const int o = og * 64 + fm * 16 + rr;
    bb[fm] = br[o];
    const float qv = q[b * DIM + o] + bb[fm];
    const float vv = v[o];
#pragma unroll
    for (int fn = 0; fn < 4; ++fn) {
      f32x4 a = acc[fm][fn];
      f32x4 th;
      th.x = tanh_fast(a.x + qv);
      th.y = tanh_fast(a.y + qv);
      th.z = tanh_fast(a.z + qv);
      th.w = tanh_fast(a.w + qv);
      usA[fn] += vv * th;
    }
  }
#pragma unroll
  for (int fn = 0; fn < 4; ++fn) {
    f32x4 us = usA[fn];
#pragma unroll
    for (int msk = 1; msk <= 8; msk <<= 1) {  // reduce over rr (o dim)
      us.x += __shfl_xor(us.x, msk);
      us.y += __shfl_xor(us.y, msk);
      us.z += __shfl_xor(us.z, msk);
      us.w += __shfl_xor(us.w, msk);
    }
    if (rr == 0)
      *(f32x4*)&u_lds[wid][fn * 16 + kg * 4] = us;
  }

  // ---- e-store: 16 ping-pong repack phases; store = 2 rows x 512 B ----
#pragma unroll 2
  for (int ph = 0; ph < 16; ++ph) {
    float* Eb = &Ebuf[ph & 1][0];
    if (og == (ph >> 1)) {
      const int f2b = (ph & 1) * 2;
#pragma unroll
      for (int f2 = 0; f2 < 2; ++f2) {
        const int fm = f2b + f2;
#pragma unroll
        for (int fn = 0; fn < 4; ++fn) {
          f32x4 ev = acc[fm][fn] + bb[fm];
          *(f32x4*)&Eb[(f2 * 16 + rr) * 132 + lg * 64 + fn * 16 + kg * 4] = ev;
        }
      }
    }
    __syncthreads();
    {
      const int op = tid >> 5, lc4 = (tid & 31) * 4;
      f32x4 ev = *(const f32x4*)&Eb[op * 132 + lc4];
      __builtin_nontemporal_store(
          ev, (f32x4*)&e_out[((size_t)(b * DIM + ph * 32 + op)) * L_ + l0 + lc4]);
    }
  }

  // ---- logits ----
  __syncthreads();
  if (tid < 128) {
    const int ll = tid & 63, lgi = tid >> 6;
    float s = 0.f;
#pragma unroll
    for (int o8 = 0; o8 < 8; ++o8) s += u_lds[o8 * 2 + lgi][ll];
    logits[(size_t)b * L_ + l0 + lgi * 64 + ll] = s;
  }
}

extern "C" void kernel_launch(void* const* d_in, const int* in_sizes, int n_in,
                              void* d_out, int out_size, void* d_ws, size_t ws_size,
                              hipStream_t stream) {
  const float* query = (const float*)d_in[0];
  const float* ref   = (const float*)d_in[1];
  const float* Wq    = (const float*)d_in[2];
  const float* bq    = (const float*)d_in[3];
  const float* Wr    = (const float*)d_in[4];
  const float* br    = (const float*)d_in[5];
  const float* v     = (const float*)d_in[6];

  float* e_out  = (float*)d_out;
  float* logits = e_out + (size_t)B_ * DIM * L_;  // 67108864

  char* ws = (char*)d_ws;
  u16*   Wrbt = (u16*)ws;               // 512 KB [16][512][32]
  float* q    = (float*)(ws + 524288);  // 128 KB

  prep_kernel<<<128, 256, 0, stream>>>(query, Wq, bq, Wr, q, Wrbt);
  gemm_fused<<<dim3(64, 16), 1024, 0, stream>>>(ref, Wrbt, q, br, v, e_out, logits);
}

// Round 17
// 214.803 us; speedup vs baseline: 5.0733x; 1.0379x over previous
//
#include <hip/hip_runtime.h>

#define DIM 512
#define B_  64
#define L_  2048

typedef unsigned short u16;
typedef float f32x4 __attribute__((ext_vector_type(4)));
typedef short s16x8 __attribute__((ext_vector_type(8)));
typedef short s16x4 __attribute__((ext_vector_type(4)));

__device__ __forceinline__ u16 f2bf(float f) {
  union { float f; unsigned u; } x{f};
  unsigned r = x.u + 0x7FFFu + ((x.u >> 16) & 1u);
  return (u16)(r >> 16);
}

__device__ __forceinline__ float tanh_fast(float x) {
  float e2 = __expf(2.0f * x);
  return 1.0f - 2.0f / (e2 + 1.0f);
}

// ---------- prep: q = query @ Wq^T + bq ; Wr -> bf16 transposed [t][o][32k] ----------
__global__ __launch_bounds__(256) void prep_kernel(
    const float* __restrict__ query, const float* __restrict__ Wq,
    const float* __restrict__ bq, const float* __restrict__ Wr,
    float* __restrict__ q_out, u16* __restrict__ Wrbt) {
  const int blk = blockIdx.x;
  const int tid = threadIdx.x;
  if (blk < 64) {
    __shared__ float qs[DIM];
    for (int i = tid; i < DIM; i += 256) qs[i] = query[blk * DIM + i];
    __syncthreads();
    for (int o = tid; o < DIM; o += 256) {
      const float* w = Wq + o * DIM;
      float acc = 0.f;
      for (int k = 0; k < DIM; k += 4) {
        f32x4 a = *(const f32x4*)&qs[k];
        f32x4 b = *(const f32x4*)&w[k];
        acc += a.x * b.x + a.y * b.y + a.z * b.z + a.w * b.w;
      }
      q_out[blk * DIM + o] = acc + bq[o];
    }
  } else {
    const int c = blk - 64;
    const int flat = c * 4096 + tid * 16;
    const int o = flat >> 9, k0 = flat & 511;
    const int t = k0 >> 5, kk = k0 & 31;
    u16* dst = Wrbt + t * 16384 + o * 32 + kk;
#pragma unroll
    for (int i = 0; i < 4; ++i) {
      f32x4 a = *(const f32x4*)&Wr[flat + i * 4];
      s16x4 o4;
      o4.x = (short)f2bf(a.x); o4.y = (short)f2bf(a.y);
      o4.z = (short)f2bf(a.z); o4.w = (short)f2bf(a.w);
      *(s16x4*)&dst[i * 4] = o4;
    }
  }
}

// ---------- fused GEMM: 512o x 128l; depth-2 ref prefetch + af ping-pong ----------
// R16 structure. New: af (Wrbt) fragments for step t+1 are issued at the TOP of
// step t into the other ping-pong buffer (static afP/afQ via unroll-by-2), so
// they cross the counted barrier in flight and the L2 latency is hidden under
// the step. s_setprio(1) around the MFMA cluster (T5).
__global__ __launch_bounds__(1024, 4) void gemm_fused(
    const float* __restrict__ ref, const u16* __restrict__ Wrbt,
    const float* __restrict__ q, const float* __restrict__ br,
    const float* __restrict__ v, float* __restrict__ e_out,
    float* __restrict__ logits) {
  __shared__ u16 Bs[2][128 * 40];      // 20,480 B
  __shared__ float Ebuf[2][32 * 132];  // 33,792 B
  __shared__ float u_lds[16][64];      //  4,096 B

  const int b = blockIdx.x, lt = blockIdx.y;
  const int l0 = lt * 128;
  const int tid = threadIdx.x, lane = tid & 63, wid = tid >> 6;
  const int og = wid >> 1, lg = wid & 1;
  const int rr = lane & 15, kg = lane >> 4;
  const int srow = tid >> 3, sc8 = tid & 7;

  const size_t refbase = ((size_t)(l0 + srow) * 64 + b) * 512 + sc8 * 4;
  const u16* ap = Wrbt + (og * 64 + rr) * 32 + kg * 8;

  // ---- prologue: stage slice 0; issue slice 1 + af[0]; counted barrier ----
  f32x4 srIF;
  s16x8 afP[4], afQ[4];
  {
    f32x4 a = __builtin_nontemporal_load((const f32x4*)&ref[refbase]);
    s16x4 o4;
    o4.x = (short)f2bf(a.x); o4.y = (short)f2bf(a.y);
    o4.z = (short)f2bf(a.z); o4.w = (short)f2bf(a.w);
    *(s16x4*)&Bs[0][srow * 40 + sc8 * 4] = o4;
    srIF = __builtin_nontemporal_load((const f32x4*)&ref[refbase + 32]);
#pragma unroll
    for (int fm = 0; fm < 4; ++fm)
      afP[fm] = *(const s16x8*)(ap + fm * 512);
  }
  asm volatile("s_waitcnt lgkmcnt(0)" ::: "memory");
  __builtin_amdgcn_s_barrier();
  __builtin_amdgcn_sched_barrier(0);

  f32x4 acc[4][4];
#pragma unroll
  for (int fm = 0; fm < 4; ++fm)
#pragma unroll
    for (int fn = 0; fn < 4; ++fn) acc[fm][fn] = (f32x4){0.f, 0.f, 0.f, 0.f};

#pragma unroll
  for (int tt = 0; tt < 8; ++tt) {
    const int t0 = tt * 2, t1 = t0 + 1;
    // ======== step t0: Bs[0], MFMA with afP; prefetch afQ = af[t1] ========
    {
      f32x4 srN;
      if (t0 < 14)
        srN = __builtin_nontemporal_load((const f32x4*)&ref[refbase + (t0 + 2) * 32]);
#pragma unroll
      for (int fm = 0; fm < 4; ++fm)
        afQ[fm] = *(const s16x8*)(ap + t1 * 16384 + fm * 512);
      s16x8 bf[4];
#pragma unroll
      for (int fn = 0; fn < 4; ++fn)
        bf[fn] = *(const s16x8*)&Bs[0][(lg * 64 + fn * 16 + rr) * 40 + kg * 8];
      __builtin_amdgcn_s_setprio(1);
#pragma unroll
      for (int fm = 0; fm < 4; ++fm)
#pragma unroll
        for (int fn = 0; fn < 4; ++fn)
          acc[fm][fn] = __builtin_amdgcn_mfma_f32_16x16x32_bf16(bf[fn], afP[fm], acc[fm][fn], 0, 0, 0);
      __builtin_amdgcn_s_setprio(0);
      {  // stage slice t0+1 into Bs[1]
        s16x4 o4;
        o4.x = (short)f2bf(srIF.x); o4.y = (short)f2bf(srIF.y);
        o4.z = (short)f2bf(srIF.z); o4.w = (short)f2bf(srIF.w);
        *(s16x4*)&Bs[1][srow * 40 + sc8 * 4] = o4;
      }
      asm volatile("s_waitcnt lgkmcnt(0)" ::: "memory");
      __builtin_amdgcn_s_barrier();
      __builtin_amdgcn_sched_barrier(0);
      if (t0 < 14) srIF = srN;
    }
    // ======== step t1: Bs[1], MFMA with afQ; prefetch afP = af[t1+1] ========
    {
      f32x4 srN;
      if (t1 < 14)
        srN = __builtin_nontemporal_load((const f32x4*)&ref[refbase + (t1 + 2) * 32]);
      if (t1 < 15)
#pragma unroll
        for (int fm = 0; fm < 4; ++fm)
          afP[fm] = *(const s16x8*)(ap + (t1 + 1) * 16384 + fm * 512);
      s16x8 bf[4];
#pragma unroll
      for (int fn = 0; fn < 4; ++fn)
        bf[fn] = *(const s16x8*)&Bs[1][(lg * 64 + fn * 16 + rr) * 40 + kg * 8];
      __builtin_amdgcn_s_setprio(1);
#pragma unroll
      for (int fm = 0; fm < 4; ++fm)
#pragma unroll
        for (int fn = 0; fn < 4; ++fn)
          acc[fm][fn] = __builtin_amdgcn_mfma_f32_16x16x32_bf16(bf[fn], afQ[fm], acc[fm][fn], 0, 0, 0);
      __builtin_amdgcn_s_setprio(0);
      if (t1 < 15) {
        {  // stage slice t1+1 into Bs[0]
          s16x4 o4;
          o4.x = (short)f2bf(srIF.x); o4.y = (short)f2bf(srIF.y);
          o4.z = (short)f2bf(srIF.z); o4.w = (short)f2bf(srIF.w);
          *(s16x4*)&Bs[0][srow * 40 + sc8 * 4] = o4;
        }
        asm volatile("s_waitcnt lgkmcnt(0)" ::: "memory");
        __builtin_amdgcn_s_barrier();
        __builtin_amdgcn_sched_barrier(0);
        if (t1 < 14) srIF = srN;
      }
    }
  }

  // ---- tanh / logits partials (register-only) ----
  float bb[4];
  f32x4 usA[4];
#pragma unroll
  for (int fn = 0; fn < 4; ++fn) usA[fn] = (f32x4){0.f, 0.f, 0.f, 0.f};
#pragma unroll
  for (int fm = 0; fm < 4; ++fm) {
    const int o = og * 64 + fm * 16 + rr;
    bb[fm] = br[o];
    const float qv = q[b * DIM + o] + bb[fm];
    const float vv = v[o];
#pragma unroll
    for (int fn = 0; fn < 4; ++fn) {
      f32x4 a = acc[fm][fn];
      f32x4 th;
      th.x = tanh_fast(a.x + qv);
      th.y = tanh_fast(a.y + qv);
      th.z = tanh_fast(a.z + qv);
      th.w = tanh_fast(a.w + qv);
      usA[fn] += vv * th;
    }
  }
#pragma unroll
  for (int fn = 0; fn < 4; ++fn) {
    f32x4 us = usA[fn];
#pragma unroll
    for (int msk = 1; msk <= 8; msk <<= 1) {  // reduce over rr (o dim)
      us.x += __shfl_xor(us.x, msk);
      us.y += __shfl_xor(us.y, msk);
      us.z += __shfl_xor(us.z, msk);
      us.w += __shfl_xor(us.w, msk);
    }
    if (rr == 0)
      *(f32x4*)&u_lds[wid][fn * 16 + kg * 4] = us;
  }

  // ---- e-store: 16 ping-pong repack phases; store = 2 rows x 512 B ----
#pragma unroll 2
  for (int ph = 0; ph < 16; ++ph) {
    float* Eb = &Ebuf[ph & 1][0];
    if (og == (ph >> 1)) {
      const int f2b = (ph & 1) * 2;
#pragma unroll
      for (int f2 = 0; f2 < 2; ++f2) {
        const int fm = f2b + f2;
#pragma unroll
        for (int fn = 0; fn < 4; ++fn) {
          f32x4 ev = acc[fm][fn] + bb[fm];
          *(f32x4*)&Eb[(f2 * 16 + rr) * 132 + lg * 64 + fn * 16 + kg * 4] = ev;
        }
      }
    }
    __syncthreads();
    {
      const int op = tid >> 5, lc4 = (tid & 31) * 4;
      f32x4 ev = *(const f32x4*)&Eb[op * 132 + lc4];
      __builtin_nontemporal_store(
          ev, (f32x4*)&e_out[((size_t)(b * DIM + ph * 32 + op)) * L_ + l0 + lc4]);
    }
  }

  // ---- logits ----
  __syncthreads();
  if (tid < 128) {
    const int ll = tid & 63, lgi = tid >> 6;
    float s = 0.f;
#pragma unroll
    for (int o8 = 0; o8 < 8; ++o8) s += u_lds[o8 * 2 + lgi][ll];
    logits[(size_t)b * L_ + l0 + lgi * 64 + ll] = s;
  }
}

extern "C" void kernel_launch(void* const* d_in, const int* in_sizes, int n_in,
                              void* d_out, int out_size, void* d_ws, size_t ws_size,
                              hipStream_t stream) {
  const float* query = (const float*)d_in[0];
  const float* ref   = (const float*)d_in[1];
  const float* Wq    = (const float*)d_in[2];
  const float* bq    = (const float*)d_in[3];
  const float* Wr    = (const float*)d_in[4];
  const float* br    = (const float*)d_in[5];
  const float* v     = (const float*)d_in[6];

  float* e_out  = (float*)d_out;
  float* logits = e_out + (size_t)B_ * DIM * L_;  // 67108864

  char* ws = (char*)d_ws;
  u16*   Wrbt = (u16*)ws;               // 512 KB [16][512][32]
  float* q    = (float*)(ws + 524288);  // 128 KB

  prep_kernel<<<128, 256, 0, stream>>>(query, Wq, bq, Wr, q, Wrbt);
  gemm_fused<<<dim3(64, 16), 1024, 0, stream>>>(ref, Wrbt, q, br, v, e_out, logits);
}